// Round 2
// baseline (178.491 us; speedup 1.0000x reference)
//
#include <hip/hip_runtime.h>
#include <math.h>

#define NU_F 0.0031830988618379067f
#define HS 136   // halves per H row: 17*8 -> 16B-aligned, stride 272B = 16 mod 128 -> reads tile banks perfectly

typedef __attribute__((ext_vector_type(8))) _Float16 half8;
typedef __attribute__((ext_vector_type(16))) float f32x16;

// tanh via exp2 + fast rcp: ~5 VALU (2 on trans pipe). inf-safe: e=inf -> 1, e=0 -> -1.
__device__ __forceinline__ float fast_tanh(float x) {
    const float e = __builtin_amdgcn_exp2f(x * 2.8853900817779268f);  // e^(2x)
    const float r = __builtin_amdgcn_rcpf(e + 1.f);
    return fmaf(-2.f, r, 1.f);
}

// pack two f32 -> one b32 of two f16 (RTE via scalar casts; compiler emits cvt+pack)
__device__ __forceinline__ uint32_t pack2(float x, float y) {
    union { _Float16 h[2]; uint32_t u; } r;
    r.h[0] = (_Float16)x; r.h[1] = (_Float16)y;
    return r.u;
}

template<int CTRL>
__device__ __forceinline__ uint32_t qperm(uint32_t v) {
    return (uint32_t)__builtin_amdgcn_update_dpp(0, (int)v, CTRL, 0xF, 0xF, true);
}

// 4x4 f16 transpose across a lane quad. In: lane c holds A=(M[0][c],M[1][c]),
// B=(M[2][c],M[3][c]) packed lo/hi. Out: lane r holds A=(M[r][0],M[r][1]),
// B=(M[r][2],M[r][3]). selM/qup precomputed per lane. 8 VALU, no DS.
__device__ __forceinline__ void quad_transpose(uint32_t &A, uint32_t &B,
                                               uint32_t selM, bool qup) {
    const uint32_t X = qperm<0xB1>(A);          // lane^1
    const uint32_t Y = qperm<0xB1>(B);
    const uint32_t u = __builtin_amdgcn_perm(A, X, selM);  // rows (l&1), col-pair (l>>1)
    const uint32_t v = __builtin_amdgcn_perm(B, Y, selM);  // rows 2+(l&1)
    const uint32_t U2 = qperm<0x4E>(u);         // lane^2
    const uint32_t V2 = qperm<0x4E>(v);
    A = qup ? V2 : u;
    B = qup ? v  : U2;
}

// ---------------------------------------------------------------------------
// Weight prep: W[l][k][n] fp32 -> k-tiled fp16:
//   idx = l*16384 + (k>>4)*2048 + n*16 + (k&15)
// A wave's per-kt B-read (16 halves/lane, n-contiguous) is one 1KB block.
// ---------------------------------------------------------------------------
__global__ void prep_kernel(const float* __restrict__ W1,
                            const float* __restrict__ W2,
                            const float* __restrict__ W3,
                            _Float16* __restrict__ ws)
{
    const int g = blockIdx.x * 256 + threadIdx.x;   // 0..49151
    const int l = g >> 14;
    const int r = g & 16383;
    const int n = r & 127;
    const int k = r >> 7;
    const float* W = (l == 0) ? W1 : (l == 1) ? W2 : W3;
    const float w = W[k * 128 + n];
    ws[l * 16384 + (k >> 4) * 2048 + n * 16 + (k & 15)] = (_Float16)w;
}

// ---------------------------------------------------------------------------
// M=64 blocks, 2x2 wave tiling (DS-pipe reduction restructure):
//   Blocks 0..8191: equation, 16 pts (rows m = 4p + channel).
//   Blocks 8192..8319: init/bound forward-only, 64 pts (m = p).
// Wave w = (wr,wc): rows [32wr,32wr+32) x cols [64wc,64wc+64).
//   - each ds_read_b128 A-frag feeds 2 MFMAs (8 reads/layer/wave, was 16)
//   - epilogue 4x4 quad-transpose in registers -> 8 ds_write_b64
//     (was 32 ds_write_b16); chain rule stays lane-local (quad = the 4
//     channels of one point, transposed after the chain rule).
// DS instrs/wave/layer: 48 -> 16.
// ---------------------------------------------------------------------------
__launch_bounds__(256, 4)
__global__ void pinn_kernel(const float* __restrict__ tx_eq,
                            const float* __restrict__ tx_init,
                            const float* __restrict__ tx_bnd,
                            const float* __restrict__ W0, const float* __restrict__ b0,
                            const float* __restrict__ b1, const float* __restrict__ b2,
                            const float* __restrict__ b3,
                            const float* __restrict__ W4, const float* __restrict__ b4,
                            const _Float16* __restrict__ wt,
                            float* __restrict__ out)
{
    __shared__ _Float16 Hh[64][HS];   // 17.4 KB, in-place across layers

    const int tid   = threadIdx.x;
    const int blk   = blockIdx.x;
    const bool is_eq = (blk < 8192);
    const int w     = tid >> 6;
    const int lane  = tid & 63;
    const int col   = lane & 31;
    const int khalf = lane >> 5;
    const int wr    = w >> 1;
    const int wc    = w & 1;
    const int ncol0 = 64 * wc + col;          // acc0 column; acc1 = +32
    const int arow  = 32 * wr + col;          // A-frag row
    const uint32_t selM = (lane & 1) ? 0x07060302u : 0x01000504u;
    const bool qup = (lane & 2) != 0;

    // ---- input layer (K=2, pointwise, fp32) ----
    if (is_eq) {
        const int p  = tid >> 4;                 // 0..15
        const int fb = (tid & 15) * 8;
        const float tv = tx_eq[blk * 32 + 2 * p];
        const float xv = tx_eq[blk * 32 + 2 * p + 1];
        const int m0 = 4 * p;
        float vch[4][8];
        #pragma unroll
        for (int j = 0; j < 8; ++j) {
            const int f = fb + j;
            const float w0v = W0[f];             // dz/dt
            const float w1v = W0[128 + f];       // dz/dx
            const float z = fmaf(tv, w0v, fmaf(xv, w1v, b0[f]));
            const float a = fast_tanh(z);
            const float s = 1.f - a * a;
            vch[0][j] = a;
            vch[1][j] = s * w0v;
            vch[2][j] = s * w1v;
            vch[3][j] = -2.f * a * s * w1v * w1v;
        }
        #pragma unroll
        for (int c = 0; c < 4; ++c) {
            half8 hh;
            #pragma unroll
            for (int j = 0; j < 8; ++j) hh[j] = (_Float16)vch[c][j];
            *(half8*)&Hh[m0 + c][fb] = hh;
        }
    } else {
        const int p  = tid >> 2;                 // 0..63 == row m
        const int f0 = (tid & 3) * 32;
        const int gp = (blk - 8192) * 64 + p;
        const float* src = (gp < 4096) ? tx_init : tx_bnd;
        const int idx = (gp < 4096) ? gp : gp - 4096;
        const float tv = src[2 * idx];
        const float xv = src[2 * idx + 1];
        #pragma unroll
        for (int g = 0; g < 4; ++g) {
            half8 hh;
            #pragma unroll
            for (int j = 0; j < 8; ++j) {
                const int f = f0 + 8 * g + j;
                hh[j] = (_Float16)fast_tanh(fmaf(tv, W0[f], fmaf(xv, W0[128 + f], b0[f])));
            }
            *(half8*)&Hh[p][f0 + 8 * g] = hh;
        }
    }
    __syncthreads();

    const float* barr[3] = {b1, b2, b3};

    #pragma unroll 1
    for (int layer = 0; layer < 3; ++layer) {
        const _Float16* __restrict__ ph = wt + layer * 16384 + ncol0 * 16 + khalf * 8;
        const float bias0 = barr[layer][ncol0];
        const float bias1 = barr[layer][ncol0 + 32];

        // both n-tiles' B in 16 named registers; loads issued back-to-back.
        half8 q0 = *(const half8*)(ph);
        half8 q1 = *(const half8*)(ph + 2048);
        half8 q2 = *(const half8*)(ph + 4096);
        half8 q3 = *(const half8*)(ph + 6144);
        half8 q4 = *(const half8*)(ph + 8192);
        half8 q5 = *(const half8*)(ph + 10240);
        half8 q6 = *(const half8*)(ph + 12288);
        half8 q7 = *(const half8*)(ph + 14336);
        half8 r0 = *(const half8*)(ph + 512);          // +32 cols
        half8 r1 = *(const half8*)(ph + 512 + 2048);
        half8 r2 = *(const half8*)(ph + 512 + 4096);
        half8 r3 = *(const half8*)(ph + 512 + 6144);
        half8 r4 = *(const half8*)(ph + 512 + 8192);
        half8 r5 = *(const half8*)(ph + 512 + 10240);
        half8 r6 = *(const half8*)(ph + 512 + 12288);
        half8 r7 = *(const half8*)(ph + 512 + 14336);

        // acc pre-loaded with bias: channel-0 rows get bias, tangent rows 0
        // (eq); ib: all rows are values -> all get bias.
        f32x16 acc0, acc1;
        #pragma unroll
        for (int e = 0; e < 16; ++e) {
            acc0[e] = (is_eq && (e & 3) != 0) ? 0.f : bias0;
            acc1[e] = (is_eq && (e & 3) != 0) ? 0.f : bias1;
        }

#define KSTEP(KT, Q, R)                                                       \
        {                                                                     \
            const half8 a = *(const half8*)&Hh[arow][KT * 16 + khalf * 8];    \
            acc0 = __builtin_amdgcn_mfma_f32_32x32x16_f16(a, Q, acc0, 0, 0, 0); \
            acc1 = __builtin_amdgcn_mfma_f32_32x32x16_f16(a, R, acc1, 0, 0, 0); \
        }
        KSTEP(0, q0, r0) KSTEP(1, q1, r1) KSTEP(2, q2, r2) KSTEP(3, q3, r3)
        KSTEP(4, q4, r4) KSTEP(5, q5, r5) KSTEP(6, q6, r6) KSTEP(7, q7, r7)
#undef KSTEP

        // epilogue COMPUTE (registers only, before the barrier). C-layout:
        // reg group 4g..4g+3 = rows 32wr+8g+4khalf+{0..3} = the 4 derivative
        // channels of one point (eq) -> chain rule in registers, then 4x4
        // quad-transpose so each lane holds 1 row x 4 consecutive cols.
        uint32_t tA[2][4], tB[2][4];
        #pragma unroll
        for (int nt = 0; nt < 2; ++nt)
            #pragma unroll
            for (int g = 0; g < 4; ++g) {
                const float A0 = (nt == 0 ? acc0 : acc1)[4 * g + 0];
                const float A1 = (nt == 0 ? acc0 : acc1)[4 * g + 1];
                const float A2 = (nt == 0 ? acc0 : acc1)[4 * g + 2];
                const float A3 = (nt == 0 ? acc0 : acc1)[4 * g + 3];
                float h0, h1, h2, h3;
                if (is_eq) {
                    const float t = fast_tanh(A0);       // bias already in acc
                    const float s = 1.f - t * t;
                    h0 = t;
                    h1 = s * A1;
                    h2 = s * A2;
                    h3 = fmaf(s, A3, -2.f * t * s * A2 * A2);
                } else {
                    h0 = fast_tanh(A0);
                    h1 = fast_tanh(A1);
                    h2 = fast_tanh(A2);
                    h3 = fast_tanh(A3);
                }
                uint32_t pa = pack2(h0, h1);
                uint32_t pb = pack2(h2, h3);
                quad_transpose(pa, pb, selM, qup);
                tA[nt][g] = pa;
                tB[nt][g] = pb;
            }

        __syncthreads();   // all reads of H done -> in-place overwrite safe

        // epilogue STORE: 8 ds_write_b64 (lane l&3 holds row mrow0+(l&3),
        // cols quad-aligned) -- the only work between the two barriers.
        {
            _Float16* vst = &Hh[32 * wr + 4 * khalf + (lane & 3)][64 * wc + (col & ~3)];
            #pragma unroll
            for (int nt = 0; nt < 2; ++nt)
                #pragma unroll
                for (int g = 0; g < 4; ++g) {
                    uint2 val;
                    val.x = tA[nt][g];
                    val.y = tB[nt][g];
                    *(uint2*)(vst + g * 8 * HS + nt * 32) = val;
                }
        }
        __syncthreads();
    }

    // ---- final layer (128 -> 1): thread t reduces k-quarter (t&3) of row t>>2
    {
        const float b4v = b4[0];
        const int m = tid >> 2;
        const int q = tid & 3;
        float dot = 0.f;
        #pragma unroll
        for (int g = 0; g < 4; ++g) {
            const int f = 32 * q + 8 * g;
            const half8 hh = *(const half8*)&Hh[m][f];
            const float4 wa = *(const float4*)&W4[f];
            const float4 wb = *(const float4*)&W4[f + 4];
            dot = fmaf((float)hh[0], wa.x, dot);
            dot = fmaf((float)hh[1], wa.y, dot);
            dot = fmaf((float)hh[2], wa.z, dot);
            dot = fmaf((float)hh[3], wa.w, dot);
            dot = fmaf((float)hh[4], wb.x, dot);
            dot = fmaf((float)hh[5], wb.y, dot);
            dot = fmaf((float)hh[6], wb.z, dot);
            dot = fmaf((float)hh[7], wb.w, dot);
        }
        dot += __shfl_xor(dot, 1);
        dot += __shfl_xor(dot, 2);   // full row-dot at all 4 lanes of the group

        if (is_eq) {
            // wave w holds rows [16w,16w+16) = points [4w,4w+4);
            // row r (=4j+c) of local point j sits at lanes 16j+4c (+q).
            const int j = lane >> 4;
            const int base = 16 * j;
            const float uu   = __shfl(dot, base + 0) + b4v;
            const float utv  = __shfl(dot, base + 4);
            const float uxv  = __shfl(dot, base + 8);
            const float uxxv = __shfl(dot, base + 12);
            if ((lane & 15) == 0)
                out[blk * 16 + 4 * w + j] = fmaf(uu, uxv, utv) - NU_F * uxxv;
        } else {
            if (q == 0)
                out[131072 + (blk - 8192) * 64 + m] = dot + b4v;
        }
    }
}

extern "C" void kernel_launch(void* const* d_in, const int* in_sizes, int n_in,
                              void* d_out, int out_size, void* d_ws, size_t ws_size,
                              hipStream_t stream)
{
    const float* tx_eq   = (const float*)d_in[0];
    const float* tx_init = (const float*)d_in[1];
    const float* tx_bnd  = (const float*)d_in[2];
    const float* W0 = (const float*)d_in[3];
    const float* b0 = (const float*)d_in[4];
    const float* W1 = (const float*)d_in[5];
    const float* b1 = (const float*)d_in[6];
    const float* W2 = (const float*)d_in[7];
    const float* b2 = (const float*)d_in[8];
    const float* W3 = (const float*)d_in[9];
    const float* b3 = (const float*)d_in[10];
    const float* W4 = (const float*)d_in[11];
    const float* b4 = (const float*)d_in[12];
    float* out = (float*)d_out;
    _Float16* wt = (_Float16*)d_ws;   // needs 98304 B

    hipLaunchKernelGGL(prep_kernel, dim3(192), dim3(256), 0, stream, W1, W2, W3, wt);
    // 8192 eq blocks (16 pts) + 128 ib blocks (64 pts)
    hipLaunchKernelGGL(pinn_kernel, dim3(8320), dim3(256), 0, stream,
                       tx_eq, tx_init, tx_bnd, W0, b0, b1, b2, b3, W4, b4,
                       (const _Float16*)wt, out);
}

// Round 3
// 163.153 us; speedup vs baseline: 1.0940x; 1.0940x over previous
//
#include <hip/hip_runtime.h>
#include <math.h>

#define NU_F 0.0031830988618379067f
#define HS 136   // halves per H row: 17*8 -> 16B-aligned, odd 16B-stride = bank-balanced

typedef __attribute__((ext_vector_type(8))) _Float16 half8;
typedef __attribute__((ext_vector_type(4))) _Float16 half4;
typedef __attribute__((ext_vector_type(16))) float f32x16;

// tanh via exp2 + fast rcp: ~5 VALU (2 on trans pipe). inf-safe: e=inf -> 1, e=0 -> -1.
__device__ __forceinline__ float fast_tanh(float x) {
    const float e = __builtin_amdgcn_exp2f(x * 2.8853900817779268f);  // e^(2x)
    const float r = __builtin_amdgcn_rcpf(e + 1.f);
    return fmaf(-2.f, r, 1.f);
}

// ---------------------------------------------------------------------------
// Weight prep: W[l][k][n] fp32 -> k-tiled fp16:
//   idx = l*16384 + (k>>4)*2048 + n*16 + (k&15)
// A wave's per-kt B-read (16 halves/lane, n-contiguous) is one 1KB block.
// ---------------------------------------------------------------------------
__global__ void prep_kernel(const float* __restrict__ W1,
                            const float* __restrict__ W2,
                            const float* __restrict__ W3,
                            _Float16* __restrict__ ws)
{
    const int g = blockIdx.x * 256 + threadIdx.x;   // 0..49151
    const int l = g >> 14;
    const int r = g & 16383;
    const int n = r & 127;
    const int k = r >> 7;
    const float* W = (l == 0) ? W1 : (l == 1) ? W2 : W3;
    const float w = W[k * 128 + n];
    ws[l * 16384 + (k >> 4) * 2048 + n * 16 + (k & 15)] = (_Float16)w;
}

// ---------------------------------------------------------------------------
// R0 structure (proven best: M=128, 1x4 N-split, 4 blk/CU) + two
// instruction-negative deltas:
//   - Z-trick: one永 zero f32x16 as the C-src of each layer's first KSTEP
//     -> no per-layer accumulator re-init (saves 192 init movs/wave).
//   - B software-pipeline: layer-0 B loads issue before the input barrier;
//     layer L+1's B loads issue right after layer L's MFMAs consume the
//     registers -> L2 latency hides under epilogue + barriers, not inside
//     the barrier-to-barrier critical path.
// Blocks 0..4095: equation, 32 pts (M=128 rows, m = 4p + channel).
// Blocks 4096..4159: init/bound forward-only, 128 pts (m = p).
// Wave w computes cols [32w,32w+32) for all 128 rows (mt=0..3).
// ---------------------------------------------------------------------------
__launch_bounds__(256, 4)
__global__ void pinn_kernel(const float* __restrict__ tx_eq,
                            const float* __restrict__ tx_init,
                            const float* __restrict__ tx_bnd,
                            const float* __restrict__ W0, const float* __restrict__ b0,
                            const float* __restrict__ b1, const float* __restrict__ b2,
                            const float* __restrict__ b3,
                            const float* __restrict__ W4, const float* __restrict__ b4,
                            const _Float16* __restrict__ wt,
                            float* __restrict__ out)
{
    __shared__ _Float16 Hh[128][HS];   // 34.8 KB, in-place across layers

    const int tid   = threadIdx.x;
    const int blk   = blockIdx.x;
    const bool is_eq = (blk < 4096);
    const int w     = tid >> 6;
    const int lane  = tid & 63;
    const int col   = lane & 31;
    const int khalf = lane >> 5;
    const int ncol  = 32 * w + col;
    const int wofs  = ncol * 16 + khalf * 8;

    // ---- earliest VMEM: the point coordinates (oldest in queue) ----
    float tv, xv;
    if (is_eq) {
        const float2 t2 = ((const float2*)tx_eq)[blk * 32 + (tid >> 3)];
        tv = t2.x; xv = t2.y;
    } else {
        const int p  = tid >> 1;
        const int gp = (blk - 4096) * 128 + p;
        const float2* src = (gp < 4096) ? (const float2*)tx_init : (const float2*)tx_bnd;
        const int idx = (gp < 4096) ? gp : gp - 4096;
        const float2 t2 = src[idx];
        tv = t2.x; xv = t2.y;
    }

    // ---- layer-0 B prefetch: issued here, consumed after the input barrier ----
    const _Float16* ph = wt + wofs;
    half8 q0 = *(const half8*)(ph);
    half8 q1 = *(const half8*)(ph + 2048);
    half8 q2 = *(const half8*)(ph + 4096);
    half8 q3 = *(const half8*)(ph + 6144);
    half8 q4 = *(const half8*)(ph + 8192);
    half8 q5 = *(const half8*)(ph + 10240);
    half8 q6 = *(const half8*)(ph + 12288);
    half8 q7 = *(const half8*)(ph + 14336);

    // never-written zero C-operand (init once, reused all 3 layers)
    f32x16 Z;
    #pragma unroll
    for (int e = 0; e < 16; ++e) Z[e] = 0.f;

    // ---- input layer (K=2, pointwise, fp32) ----
    if (is_eq) {
        const int p  = tid >> 3;                 // 0..31
        const int f0 = (tid & 7) * 16;
        const int m0 = 4 * p;
        #pragma unroll
        for (int half = 0; half < 2; ++half) {
            const int fb = f0 + 8 * half;
            float vch[4][8];
            #pragma unroll
            for (int j = 0; j < 8; ++j) {
                const int f = fb + j;
                const float w0v = W0[f];             // dz/dt
                const float w1v = W0[128 + f];       // dz/dx
                const float z = fmaf(tv, w0v, fmaf(xv, w1v, b0[f]));
                const float a = fast_tanh(z);
                const float s = 1.f - a * a;
                vch[0][j] = a;
                vch[1][j] = s * w0v;
                vch[2][j] = s * w1v;
                vch[3][j] = -2.f * a * s * w1v * w1v;
            }
            #pragma unroll
            for (int c = 0; c < 4; ++c) {
                half8 hh;
                #pragma unroll
                for (int j = 0; j < 8; ++j) hh[j] = (_Float16)vch[c][j];
                *(half8*)&Hh[m0 + c][fb] = hh;
            }
        }
    } else {
        const int p  = tid >> 1;                 // 0..127 == row m
        const int f0 = (tid & 1) * 64;
        #pragma unroll
        for (int g = 0; g < 8; ++g) {
            half8 hh;
            #pragma unroll
            for (int j = 0; j < 8; ++j) {
                const int f = f0 + 8 * g + j;
                hh[j] = (_Float16)fast_tanh(fmaf(tv, W0[f], fmaf(xv, W0[128 + f], b0[f])));
            }
            *(half8*)&Hh[p][f0 + 8 * g] = hh;
        }
    }
    __syncthreads();

    const float* barr[3] = {b1, b2, b3};

    #pragma unroll 1
    for (int layer = 0; layer < 3; ++layer) {
        const float bias = barr[layer][ncol];

        f32x16 acc0, acc1, acc2, acc3;

#define KSTEP0(Q)                                                             \
        {                                                                     \
            const int k0 = khalf * 8;                                         \
            const half8 ah0 = *(const half8*)&Hh[col][k0];                    \
            const half8 ah1 = *(const half8*)&Hh[32 + col][k0];               \
            const half8 ah2 = *(const half8*)&Hh[64 + col][k0];               \
            const half8 ah3 = *(const half8*)&Hh[96 + col][k0];               \
            acc0 = __builtin_amdgcn_mfma_f32_32x32x16_f16(ah0, Q, Z, 0, 0, 0); \
            acc1 = __builtin_amdgcn_mfma_f32_32x32x16_f16(ah1, Q, Z, 0, 0, 0); \
            acc2 = __builtin_amdgcn_mfma_f32_32x32x16_f16(ah2, Q, Z, 0, 0, 0); \
            acc3 = __builtin_amdgcn_mfma_f32_32x32x16_f16(ah3, Q, Z, 0, 0, 0); \
        }
#define KSTEP(KT, Q)                                                          \
        {                                                                     \
            const int k0 = KT * 16 + khalf * 8;                               \
            const half8 ah0 = *(const half8*)&Hh[col][k0];                    \
            const half8 ah1 = *(const half8*)&Hh[32 + col][k0];               \
            const half8 ah2 = *(const half8*)&Hh[64 + col][k0];               \
            const half8 ah3 = *(const half8*)&Hh[96 + col][k0];               \
            acc0 = __builtin_amdgcn_mfma_f32_32x32x16_f16(ah0, Q, acc0, 0, 0, 0); \
            acc1 = __builtin_amdgcn_mfma_f32_32x32x16_f16(ah1, Q, acc1, 0, 0, 0); \
            acc2 = __builtin_amdgcn_mfma_f32_32x32x16_f16(ah2, Q, acc2, 0, 0, 0); \
            acc3 = __builtin_amdgcn_mfma_f32_32x32x16_f16(ah3, Q, acc3, 0, 0, 0); \
        }
        KSTEP0(q0) KSTEP(1, q1) KSTEP(2, q2) KSTEP(3, q3)
        KSTEP(4, q4) KSTEP(5, q5) KSTEP(6, q6) KSTEP(7, q7)
#undef KSTEP0
#undef KSTEP

        // ---- next layer's B prefetch: q-regs just consumed, reload now so
        // L2 latency hides under epilogue compute + both barriers.
        if (layer < 2) {
            ph += 16384;
            q0 = *(const half8*)(ph);
            q1 = *(const half8*)(ph + 2048);
            q2 = *(const half8*)(ph + 4096);
            q3 = *(const half8*)(ph + 6144);
            q4 = *(const half8*)(ph + 8192);
            q5 = *(const half8*)(ph + 10240);
            q6 = *(const half8*)(ph + 12288);
            q7 = *(const half8*)(ph + 14336);
        }

        // epilogue COMPUTE (registers only, before the barrier). C-layout:
        // reg group 4g..4g+3 = rows mt*32+8g+4khalf+{0..3} = the 4 derivative
        // channels of one point (eq) -> chain rule in registers.
        half4 h16[4][4];
        #pragma unroll
        for (int mt = 0; mt < 4; ++mt)
            #pragma unroll
            for (int g = 0; g < 4; ++g) {
                const float A0 = (mt == 0 ? acc0 : mt == 1 ? acc1 : mt == 2 ? acc2 : acc3)[4 * g + 0];
                const float A1 = (mt == 0 ? acc0 : mt == 1 ? acc1 : mt == 2 ? acc2 : acc3)[4 * g + 1];
                const float A2 = (mt == 0 ? acc0 : mt == 1 ? acc1 : mt == 2 ? acc2 : acc3)[4 * g + 2];
                const float A3 = (mt == 0 ? acc0 : mt == 1 ? acc1 : mt == 2 ? acc2 : acc3)[4 * g + 3];
                half4 hv;
                if (is_eq) {
                    const float t = fast_tanh(A0 + bias);
                    const float s = 1.f - t * t;
                    hv[0] = (_Float16)t;
                    hv[1] = (_Float16)(s * A1);
                    hv[2] = (_Float16)(s * A2);
                    hv[3] = (_Float16)fmaf(s, A3, -2.f * t * s * A2 * A2);
                } else {
                    hv[0] = (_Float16)fast_tanh(A0 + bias);
                    hv[1] = (_Float16)fast_tanh(A1 + bias);
                    hv[2] = (_Float16)fast_tanh(A2 + bias);
                    hv[3] = (_Float16)fast_tanh(A3 + bias);
                }
                h16[mt][g] = hv;
            }

        __syncthreads();   // all reads of H done -> in-place overwrite safe

        // epilogue STORE (the only work between the two barriers)
        #pragma unroll
        for (int mt = 0; mt < 4; ++mt)
            #pragma unroll
            for (int g = 0; g < 4; ++g) {
                const int mrow0 = mt * 32 + 8 * g + 4 * khalf;
                Hh[mrow0 + 0][ncol] = h16[mt][g][0];
                Hh[mrow0 + 1][ncol] = h16[mt][g][1];
                Hh[mrow0 + 2][ncol] = h16[mt][g][2];
                Hh[mrow0 + 3][ncol] = h16[mt][g][3];
            }
        __syncthreads();
    }

    // ---- final layer (128 -> 1): thread t reduces k-half (t&1) of row t>>1
    {
        const float b4v = b4[0];
        const int m = tid >> 1;
        const int q = tid & 1;
        float dot = 0.f;
        #pragma unroll
        for (int g = 0; g < 8; ++g) {
            const int f = 64 * q + 8 * g;
            const half8 hh = *(const half8*)&Hh[m][f];
            const float4 wa = *(const float4*)&W4[f];
            const float4 wb = *(const float4*)&W4[f + 4];
            dot = fmaf((float)hh[0], wa.x, dot);
            dot = fmaf((float)hh[1], wa.y, dot);
            dot = fmaf((float)hh[2], wa.z, dot);
            dot = fmaf((float)hh[3], wa.w, dot);
            dot = fmaf((float)hh[4], wb.x, dot);
            dot = fmaf((float)hh[5], wb.y, dot);
            dot = fmaf((float)hh[6], wb.z, dot);
            dot = fmaf((float)hh[7], wb.w, dot);
        }
        dot += __shfl_xor(dot, 1);   // full row-dot at both lanes of the pair

        if (is_eq) {
            // wave w holds rows [32w,32w+32) = points [8w,8w+8);
            // row r of point pl (=4pl+c) sits at lanes 8pl+2c (+q).
            const int base = (lane & 7) * 8;
            const float uu   = __shfl(dot, base + 0) + b4v;
            const float utv  = __shfl(dot, base + 2);
            const float uxv  = __shfl(dot, base + 4);
            const float uxxv = __shfl(dot, base + 6);
            if (lane < 8)
                out[blk * 32 + 8 * w + lane] = fmaf(uu, uxv, utv) - NU_F * uxxv;
        } else {
            if (q == 0)
                out[131072 + (blk - 4096) * 128 + m] = dot + b4v;
        }
    }
}

extern "C" void kernel_launch(void* const* d_in, const int* in_sizes, int n_in,
                              void* d_out, int out_size, void* d_ws, size_t ws_size,
                              hipStream_t stream)
{
    const float* tx_eq   = (const float*)d_in[0];
    const float* tx_init = (const float*)d_in[1];
    const float* tx_bnd  = (const float*)d_in[2];
    const float* W0 = (const float*)d_in[3];
    const float* b0 = (const float*)d_in[4];
    const float* W1 = (const float*)d_in[5];
    const float* b1 = (const float*)d_in[6];
    const float* W2 = (const float*)d_in[7];
    const float* b2 = (const float*)d_in[8];
    const float* W3 = (const float*)d_in[9];
    const float* b3 = (const float*)d_in[10];
    const float* W4 = (const float*)d_in[11];
    const float* b4 = (const float*)d_in[12];
    float* out = (float*)d_out;
    _Float16* wt = (_Float16*)d_ws;   // needs 98304 B

    hipLaunchKernelGGL(prep_kernel, dim3(192), dim3(256), 0, stream, W1, W2, W3, wt);
    // 4096 eq blocks (32 pts) + 64 ib blocks (128 pts)
    hipLaunchKernelGGL(pinn_kernel, dim3(4160), dim3(256), 0, stream,
                       tx_eq, tx_init, tx_bnd, W0, b0, b1, b2, b3, W4, b4,
                       (const _Float16*)wt, out);
}